// Round 6
// baseline (810.866 us; speedup 1.0000x reference)
//
#include <hip/hip_runtime.h>

typedef _Float16 f16x8 __attribute__((ext_vector_type(8)));
typedef _Float16 f16x4 __attribute__((ext_vector_type(4)));
typedef _Float16 f16x2 __attribute__((ext_vector_type(2)));
typedef float f32x4 __attribute__((ext_vector_type(4)));

#define NTH 512
#define SEQT 256
#define LD0 200
#define LD1 200
#define LD2 168

struct KArgs { const float* in[30]; float* out; };

__device__ __forceinline__ float fast_tanh(float x) {
  return __fdividef(2.0f, 1.0f + __expf(-2.0f * x)) - 1.0f;
}
__device__ __forceinline__ float fast_sig(float x) {
  return __fdividef(1.0f, 1.0f + __expf(-x));
}

__device__ __forceinline__ f32x4 mfma16(f16x8 a, f16x8 b, f32x4 c) {
  return __builtin_amdgcn_mfma_f32_16x16x32_f16(a, b, c, 0, 0, 0);
}

__device__ __forceinline__ f16x4 combine3(const f32x4 acc[3]) {
  f16x4 v;
  #pragma unroll
  for (int q = 0; q < 4; ++q) {
    const float ff1 = fast_tanh(acc[0][q]);
    const float ff2 = fast_tanh(acc[1][q]);
    const float ti  = fast_sig(acc[2][q]);
    v[q] = (_Float16)(ff1 + ti * (ff2 - ff1));
  }
  return v;
}

// load one 3-mat tile (ff1*mask, ff2*mask, ta+tb) into wW[BASE..BASE+3*KT)
template<int BASE, int KT>
__device__ __forceinline__ void load_tile(f16x8* wW, const float* W1, const float* W2,
                                          const float* Wa, const float* Wb,
                                          const float* Mk, int n, int CAT, int H, int kb) {
  #pragma unroll
  for (int kt = 0; kt < KT; ++kt) {
    #pragma unroll
    for (int m = 0; m < 3; ++m) {
      f16x8 f;
      #pragma unroll
      for (int j = 0; j < 8; ++j) {
        const int k = kt * 32 + kb + j;
        float v = 0.f;
        if (n < H && k < CAT) {
          if (m == 0)      v = W1[n*CAT+k] * Mk[n*CAT+k];
          else if (m == 1) v = W2[n*CAT+k] * Mk[n*CAT+k];
          else             v = Wa[n*CAT+k] + Wb[n*CAT+k];
        }
        f[j] = (_Float16)v;
      }
      wW[BASE + m*KT + kt] = f;
    }
  }
}

template<int KT>
__device__ __forceinline__ void loadB(f16x8* B, const _Float16* c, int LD, int r, int kb) {
  #pragma unroll
  for (int kt = 0; kt < KT; ++kt)
    B[kt] = *reinterpret_cast<const f16x8*>(c + r*LD + kt*32 + kb);
}

template<int BASE, int KT>
__device__ __forceinline__ void mma_tile(f32x4 acc[3], const f16x8* wW, const f16x8* B) {
  #pragma unroll
  for (int kt = 0; kt < KT; ++kt)
    #pragma unroll
    for (int m = 0; m < 3; ++m)
      acc[m] = mfma16(wW[BASE + m*KT + kt], B[kt], acc[m]);
}

__device__ __forceinline__ void init3(f32x4 acc[3], const float* sb, int bs, int n0) {
  #pragma unroll
  for (int m = 0; m < 3; ++m)
    acc[m] = *reinterpret_cast<const f32x4*>(sb + m*bs + n0);
}

__device__ __forceinline__ f16x8 loadB8u(const _Float16* p) {  // 8B-aligned 16B
  const f16x4 a = *reinterpret_cast<const f16x4*>(p);
  const f16x4 b = *reinterpret_cast<const f16x4*>(p + 4);
  f16x8 v;
  v[0]=a[0]; v[1]=a[1]; v[2]=a[2]; v[3]=a[3];
  v[4]=b[0]; v[5]=b[1]; v[6]=b[2]; v[7]=b[3];
  return v;
}

__global__ __launch_bounds__(NTH, 2) void ncp_fused(KArgs args) {
  __shared__ __align__(16) _Float16 c0[2][16 * LD0];
  __shared__ __align__(16) _Float16 c1[2][16 * LD1];
  __shared__ __align__(16) _Float16 c2[2][16 * LD2];
  __shared__ __align__(16) _Float16 wt3[15 * 64 * 8];   // L2 tile-3 frags (wave 7)
  __shared__ float b0s[3 * 128], b1s[3 * 80], b2s[3 * 64], bfcs[64];

  const int tid  = threadIdx.x;
  const int w    = tid >> 6;
  const int lane = tid & 63;
  const int r    = lane & 15;      // batch row
  const int g    = lane >> 4;
  const int kb   = g * 8;
  const int wgBase = blockIdx.x * 16;
  const float* __restrict__ xg = args.in[29];

  // ---------- persistent weight fragments ----------
  // w0..3: L0 tiles 2w,2w+1 -> [0..17],[18..35]
  // w4,w5: L1 tiles 2(w-4),2(w-4)+1 -> [0..17],[18..35]
  // w6   : L1 t4 -> [0..17]; L2 t0 -> [18..32]; FC o-tiles 0,1 -> [33..36]
  // w7   : L2 t1 -> [0..14]; L2 t2 -> [15..29]; L2 t3 via LDS; FC o-tiles 2,3 -> [33..36]
  f16x8 wW[37];
  if (w < 4) {
    load_tile<0, 6>(wW, args.in[1], args.in[3], args.in[5], args.in[7], args.in[0],
                    (2*w)*16 + r, 180, 116, kb);
    load_tile<18, 6>(wW, args.in[1], args.in[3], args.in[5], args.in[7], args.in[0],
                     (2*w+1)*16 + r, 180, 116, kb);
  } else if (w < 6) {
    load_tile<0, 6>(wW, args.in[10], args.in[12], args.in[14], args.in[16], args.in[9],
                    (2*(w-4))*16 + r, 192, 76, kb);
    load_tile<18, 6>(wW, args.in[10], args.in[12], args.in[14], args.in[16], args.in[9],
                     (2*(w-4)+1)*16 + r, 192, 76, kb);
  } else if (w == 6) {
    load_tile<0, 6>(wW, args.in[10], args.in[12], args.in[14], args.in[16], args.in[9],
                    64 + r, 192, 76, kb);
    load_tile<18, 5>(wW, args.in[19], args.in[21], args.in[23], args.in[25], args.in[18],
                     r, 140, 64, kb);
  } else {
    load_tile<0, 5>(wW, args.in[19], args.in[21], args.in[23], args.in[25], args.in[18],
                    16 + r, 140, 64, kb);
    load_tile<15, 5>(wW, args.in[19], args.in[21], args.in[23], args.in[25], args.in[18],
                     32 + r, 140, 64, kb);
  }
  if (w >= 6) {   // FC fragments
    const int ot0 = (w - 6) * 2;
    #pragma unroll
    for (int tl = 0; tl < 2; ++tl)
      #pragma unroll
      for (int kt = 0; kt < 2; ++kt) {
        f16x8 f;
        #pragma unroll
        for (int j = 0; j < 8; ++j)
          f[j] = (_Float16)args.in[27][((ot0 + tl)*16 + r)*64 + kt*32 + kb + j];
        wW[33 + tl*2 + kt] = f;
      }
  }

  // ---------- LDS init ----------
  for (int u = tid; u < 15 * 64; u += NTH) {    // L2 tile-3 frags
    const int ln = u & 63;
    const int ff = u >> 6;
    const int kt = ff % 5, m = ff / 5;
    const int n  = 48 + (ln & 15);
    const int kbb = (ln >> 4) * 8;
    f16x8 f;
    #pragma unroll
    for (int j = 0; j < 8; ++j) {
      const int k = kt*32 + kbb + j;
      float v = 0.f;
      if (k < 140) {
        if (m == 0)      v = args.in[19][n*140+k] * args.in[18][n*140+k];
        else if (m == 1) v = args.in[21][n*140+k] * args.in[18][n*140+k];
        else             v = args.in[23][n*140+k] + args.in[25][n*140+k];
      }
      f[j] = (_Float16)v;
    }
    *reinterpret_cast<f16x8*>(wt3 + (size_t)u * 8) = f;
  }
  if (tid < 128) {
    b0s[tid]       = (tid < 116) ? args.in[2][tid] : 0.f;
    b0s[128 + tid] = (tid < 116) ? args.in[4][tid] : 0.f;
    b0s[256 + tid] = (tid < 116) ? args.in[6][tid] + args.in[8][tid] : 0.f;
  }
  if (tid < 80) {
    b1s[tid]       = (tid < 76) ? args.in[11][tid] : 0.f;
    b1s[80 + tid]  = (tid < 76) ? args.in[13][tid] : 0.f;
    b1s[160 + tid] = (tid < 76) ? args.in[15][tid] + args.in[17][tid] : 0.f;
  }
  if (tid < 64) {
    b2s[tid]       = args.in[20][tid];
    b2s[64 + tid]  = args.in[22][tid];
    b2s[128 + tid] = args.in[24][tid] + args.in[26][tid];
    bfcs[tid]      = args.in[28][tid];
  }
  for (int i = tid; i < 2 * 16 * LD0; i += NTH) c0[0][i] = (_Float16)0.f;
  for (int i = tid; i < 2 * 16 * LD1; i += NTH) c1[0][i] = (_Float16)0.f;
  for (int i = tid; i < 2 * 16 * LD2; i += NTH) c2[0][i] = (_Float16)0.f;
  __syncthreads();
  // stage x(0)
  const int rr = tid >> 5, cc = (tid & 31) * 2;
  {
    const float2 v = *reinterpret_cast<const float2*>(
        xg + ((size_t)(wgBase + rr) * SEQT) * 64 + cc);
    f16x2 pk; pk[0] = (_Float16)v.x; pk[1] = (_Float16)v.y;
    *reinterpret_cast<f16x2*>(c0[0] + rr * LD0 + cc) = pk;
  }
  __syncthreads();

  // incremented pointers (no 64-bit mul in loop)
  const float* xp = xg + ((size_t)(wgBase + rr) * SEQT + 1) * 64 + cc;
  float* outp = args.out + ((size_t)(wgBase + r) * SEQT) * 64 + (w - 6) * 32 + 4 * g; // used by w6/w7

  // ---------- pipelined recurrence: one barrier per phase ----------
  // phase p: L0->h0(p), L1->h1(p-1), L2->h2(p-2), FC->y(p-3)
  #pragma unroll 1
  for (int p = 0; p < SEQT + 3; ++p) {
    const int cur = p & 1, nxt = cur ^ 1;

    float2 xv;
    const bool doX = (p < SEQT - 1);
    if (doX) xv = *reinterpret_cast<const float2*>(xp);

    if (w < 4) {
      if (p < SEQT) {
        f16x8 B[6]; loadB<6>(B, c0[cur], LD0, r, kb);
        f32x4 a[3];
        const int nA = (2*w)*16 + 4*g;
        init3(a, b0s, 128, nA);
        __builtin_amdgcn_s_setprio(1);
        mma_tile<0, 6>(a, wW, B);
        __builtin_amdgcn_s_setprio(0);
        const f16x4 vA = combine3(a);
        *reinterpret_cast<f16x4*>(c1[nxt] + r*LD1 + nA)      = vA;
        *reinterpret_cast<f16x4*>(c0[nxt] + r*LD0 + 64 + nA) = vA;
        const int nB = nA + 16;
        init3(a, b0s, 128, nB);
        __builtin_amdgcn_s_setprio(1);
        mma_tile<18, 6>(a, wW, B);
        __builtin_amdgcn_s_setprio(0);
        const f16x4 vB = combine3(a);
        if (nB < 116) {
          *reinterpret_cast<f16x4*>(c1[nxt] + r*LD1 + nB)      = vB;
          *reinterpret_cast<f16x4*>(c0[nxt] + r*LD0 + 64 + nB) = vB;
        }
      }
    } else if (w < 6) {
      if (p >= 1 && p <= SEQT) {
        f16x8 B[6]; loadB<6>(B, c1[cur], LD1, r, kb);
        f32x4 a[3];
        const int nA = (2*(w-4))*16 + 4*g;
        init3(a, b1s, 80, nA);
        __builtin_amdgcn_s_setprio(1);
        mma_tile<0, 6>(a, wW, B);
        __builtin_amdgcn_s_setprio(0);
        const f16x4 vA = combine3(a);
        *reinterpret_cast<f16x4*>(c1[nxt] + r*LD1 + 116 + nA) = vA;
        *reinterpret_cast<f16x4*>(c2[nxt] + r*LD2 + nA)       = vA;
        const int nB = nA + 16;
        init3(a, b1s, 80, nB);
        __builtin_amdgcn_s_setprio(1);
        mma_tile<18, 6>(a, wW, B);
        __builtin_amdgcn_s_setprio(0);
        const f16x4 vB = combine3(a);
        *reinterpret_cast<f16x4*>(c1[nxt] + r*LD1 + 116 + nB) = vB;
        *reinterpret_cast<f16x4*>(c2[nxt] + r*LD2 + nB)       = vB;
      }
    } else if (w == 6) {
      if (p >= 3) {   // FC o-tiles 0,1 on h2(p-3)
        f32x4 fa0 = *reinterpret_cast<const f32x4*>(bfcs + 4*g);
        f32x4 fa1 = *reinterpret_cast<const f32x4*>(bfcs + 16 + 4*g);
        const f16x8 hb0 = loadB8u(c2[cur] + r*LD2 + 76 + kb);
        const f16x8 hb1 = loadB8u(c2[cur] + r*LD2 + 76 + 32 + kb);
        fa0 = mfma16(wW[33], hb0, fa0); fa0 = mfma16(wW[34], hb1, fa0);
        fa1 = mfma16(wW[35], hb0, fa1); fa1 = mfma16(wW[36], hb1, fa1);
        *reinterpret_cast<f32x4*>(outp)      = fa0;
        *reinterpret_cast<f32x4*>(outp + 16) = fa1;
        outp += 64;
      }
      if (p >= 1 && p <= SEQT) {   // L1 tile 4
        f16x8 B[6]; loadB<6>(B, c1[cur], LD1, r, kb);
        f32x4 a[3];
        const int n4 = 64 + 4*g;
        init3(a, b1s, 80, n4);
        __builtin_amdgcn_s_setprio(1);
        mma_tile<0, 6>(a, wW, B);
        __builtin_amdgcn_s_setprio(0);
        const f16x4 v4 = combine3(a);
        if (n4 < 76) {
          *reinterpret_cast<f16x4*>(c1[nxt] + r*LD1 + 116 + n4) = v4;
          *reinterpret_cast<f16x4*>(c2[nxt] + r*LD2 + n4)       = v4;
        }
      }
      if (p >= 2 && p <= SEQT + 1) {   // L2 tile 0
        f16x8 B[5]; loadB<5>(B, c2[cur], LD2, r, kb);
        f32x4 a[3];
        const int nn = 4*g;
        init3(a, b2s, 64, nn);
        __builtin_amdgcn_s_setprio(1);
        mma_tile<18, 5>(a, wW, B);
        __builtin_amdgcn_s_setprio(0);
        const f16x4 v0 = combine3(a);
        *reinterpret_cast<f16x4*>(c2[nxt] + r*LD2 + 76 + nn) = v0;
      }
    } else {
      if (p >= 3) {   // FC o-tiles 2,3
        f32x4 fa0 = *reinterpret_cast<const f32x4*>(bfcs + 32 + 4*g);
        f32x4 fa1 = *reinterpret_cast<const f32x4*>(bfcs + 48 + 4*g);
        const f16x8 hb0 = loadB8u(c2[cur] + r*LD2 + 76 + kb);
        const f16x8 hb1 = loadB8u(c2[cur] + r*LD2 + 76 + 32 + kb);
        fa0 = mfma16(wW[33], hb0, fa0); fa0 = mfma16(wW[34], hb1, fa0);
        fa1 = mfma16(wW[35], hb0, fa1); fa1 = mfma16(wW[36], hb1, fa1);
        *reinterpret_cast<f32x4*>(outp)      = fa0;
        *reinterpret_cast<f32x4*>(outp + 16) = fa1;
        outp += 64;
      }
      if (p >= 2 && p <= SEQT + 1) {   // L2 tiles 1,2 (regs) + 3 (LDS frags)
        f16x8 B[5]; loadB<5>(B, c2[cur], LD2, r, kb);
        f32x4 a[3];
        const int n1 = 16 + 4*g;
        init3(a, b2s, 64, n1);
        __builtin_amdgcn_s_setprio(1);
        mma_tile<0, 5>(a, wW, B);
        __builtin_amdgcn_s_setprio(0);
        const f16x4 v1 = combine3(a);
        *reinterpret_cast<f16x4*>(c2[nxt] + r*LD2 + 76 + n1) = v1;
        const int n2 = 32 + 4*g;
        init3(a, b2s, 64, n2);
        __builtin_amdgcn_s_setprio(1);
        mma_tile<15, 5>(a, wW, B);
        __builtin_amdgcn_s_setprio(0);
        const f16x4 v2 = combine3(a);
        *reinterpret_cast<f16x4*>(c2[nxt] + r*LD2 + 76 + n2) = v2;
        const int n3 = 48 + 4*g;
        init3(a, b2s, 64, n3);
        __builtin_amdgcn_s_setprio(1);
        #pragma unroll
        for (int kt = 0; kt < 5; ++kt) {
          #pragma unroll
          for (int m = 0; m < 3; ++m) {
            const f16x8 af = *reinterpret_cast<const f16x8*>(
                wt3 + (size_t)((m*5 + kt)*64 + lane) * 8);
            a[m] = mfma16(af, B[kt], a[m]);
          }
        }
        __builtin_amdgcn_s_setprio(0);
        const f16x4 v3 = combine3(a);
        *reinterpret_cast<f16x4*>(c2[nxt] + r*LD2 + 76 + n3) = v3;
      }
    }

    if (doX) {   // stage x(p+1) into c0[nxt][:,0:64)
      f16x2 pk; pk[0] = (_Float16)xv.x; pk[1] = (_Float16)xv.y;
      *reinterpret_cast<f16x2*>(c0[nxt] + rr * LD0 + cc) = pk;
      xp += 64;
    }
    __syncthreads();
  }
}

extern "C" void kernel_launch(void* const* d_in, const int* in_sizes, int n_in,
                              void* d_out, int out_size, void* d_ws, size_t ws_size,
                              hipStream_t stream) {
  KArgs args;
  for (int i = 0; i < 30; ++i) args.in[i] = (const float*)d_in[i];
  args.out = (float*)d_out;
  ncp_fused<<<dim3(32), dim3(NTH), 0, stream>>>(args);
}

// Round 7
// 712.715 us; speedup vs baseline: 1.1377x; 1.1377x over previous
//
#include <hip/hip_runtime.h>

typedef _Float16 f16x8 __attribute__((ext_vector_type(8)));
typedef _Float16 f16x4 __attribute__((ext_vector_type(4)));
typedef _Float16 f16x2 __attribute__((ext_vector_type(2)));
typedef float f32x4 __attribute__((ext_vector_type(4)));

#define NTH 1024
#define SEQT 256
#define LD0 200
#define LD1 200
#define LD2 168

struct KArgs { const float* in[30]; float* out; };

__device__ __forceinline__ float fast_tanh(float x) {
  return __fdividef(2.0f, 1.0f + __expf(-2.0f * x)) - 1.0f;
}
__device__ __forceinline__ float fast_sig(float x) {
  return __fdividef(1.0f, 1.0f + __expf(-x));
}

__device__ __forceinline__ f32x4 mfma16(f16x8 a, f16x8 b, f32x4 c) {
  return __builtin_amdgcn_mfma_f32_16x16x32_f16(a, b, c, 0, 0, 0);
}

__device__ __forceinline__ f16x4 combine3(const f32x4 acc[3]) {
  f16x4 v;
  #pragma unroll
  for (int q = 0; q < 4; ++q) {
    const float ff1 = fast_tanh(acc[0][q]);
    const float ff2 = fast_tanh(acc[1][q]);
    const float ti  = fast_sig(acc[2][q]);
    v[q] = (_Float16)(ff1 + ti * (ff2 - ff1));
  }
  return v;
}

// one 3-mat tile (ff1*mask, ff2*mask, ta+tb) -> wW[m*KT+kt]
template<int KT>
__device__ __forceinline__ void load_tile(f16x8* wW, const float* W1, const float* W2,
                                          const float* Wa, const float* Wb,
                                          const float* Mk, int n, int CAT, int H, int kb) {
  #pragma unroll
  for (int kt = 0; kt < KT; ++kt) {
    #pragma unroll
    for (int m = 0; m < 3; ++m) {
      f16x8 f;
      #pragma unroll
      for (int j = 0; j < 8; ++j) {
        const int k = kt * 32 + kb + j;
        float v = 0.f;
        if (n < H && k < CAT) {
          if (m == 0)      v = W1[n*CAT+k] * Mk[n*CAT+k];
          else if (m == 1) v = W2[n*CAT+k] * Mk[n*CAT+k];
          else             v = Wa[n*CAT+k] + Wb[n*CAT+k];
        }
        f[j] = (_Float16)v;
      }
      wW[m*KT + kt] = f;
    }
  }
}

// B loaded per-kt (short live range -> low VGPR pressure)
template<int KT>
__device__ __forceinline__ void mma_tile_ld(f32x4 acc[3], const f16x8* wW,
                                            const _Float16* __restrict__ c,
                                            int LD, int r, int kb) {
  #pragma unroll
  for (int kt = 0; kt < KT; ++kt) {
    const f16x8 b = *reinterpret_cast<const f16x8*>(c + r*LD + kt*32 + kb);
    #pragma unroll
    for (int m = 0; m < 3; ++m)
      acc[m] = mfma16(wW[m*KT + kt], b, acc[m]);
  }
}

__device__ __forceinline__ void init3(f32x4 acc[3], const float* sb, int bs, int n0) {
  #pragma unroll
  for (int m = 0; m < 3; ++m)
    acc[m] = *reinterpret_cast<const f32x4*>(sb + m*bs + n0);
}

__device__ __forceinline__ f16x8 loadB8u(const _Float16* p) {  // 8B-aligned 16B
  const f16x4 a = *reinterpret_cast<const f16x4*>(p);
  const f16x4 b = *reinterpret_cast<const f16x4*>(p + 4);
  f16x8 v;
  v[0]=a[0]; v[1]=a[1]; v[2]=a[2]; v[3]=a[3];
  v[4]=b[0]; v[5]=b[1]; v[6]=b[2]; v[7]=b[3];
  return v;
}

__global__ __launch_bounds__(NTH, 4) void ncp_fused(KArgs args) {
  __shared__ __align__(16) _Float16 c0[2][16 * LD0];
  __shared__ __align__(16) _Float16 c1[2][16 * LD1];
  __shared__ __align__(16) _Float16 c2[2][16 * LD2];
  __shared__ __align__(16) _Float16 wt3[15 * 64 * 8];   // L2 tile-3 frags (wave 15)
  __shared__ __align__(16) _Float16 wfcs[8 * 64 * 8];   // FC frags: (ot*2+kt)*64+lane
  __shared__ float b0s[3 * 128], b1s[3 * 80], b2s[3 * 64], bfcs[64];

  const int tid  = threadIdx.x;
  const int wv   = tid >> 6;       // 16 waves
  const int lane = tid & 63;
  const int r    = lane & 15;      // batch row
  const int g    = lane >> 4;
  const int kb   = g * 8;
  const int wgBase = blockIdx.x * 16;
  const float* __restrict__ xg = args.in[29];

  // ---------- per-wave resident weights (ONE tile-role each) ----------
  // wv 0..7 : L0 tile wv           (KT=6, 18 frags)
  // wv 8..12: L1 tile wv-8         (KT=6, 18 frags)
  // wv 13   : L2 tile 0 (KT=5) + FC o-tiles 0,1 (frags from LDS)
  // wv 14   : L2 tile 1 (KT=5) + FC o-tiles 2,3
  // wv 15   : L2 tile 2 (KT=5, regs) + tile 3 (LDS wt3)
  f16x8 wW[18];
  if (wv < 8) {
    load_tile<6>(wW, args.in[1], args.in[3], args.in[5], args.in[7], args.in[0],
                 wv*16 + r, 180, 116, kb);
  } else if (wv < 13) {
    load_tile<6>(wW, args.in[10], args.in[12], args.in[14], args.in[16], args.in[9],
                 (wv-8)*16 + r, 192, 76, kb);
  } else {
    load_tile<5>(wW, args.in[19], args.in[21], args.in[23], args.in[25], args.in[18],
                 (wv-13)*16 + r, 140, 64, kb);
  }

  // ---------- LDS init ----------
  for (int u = tid; u < 15 * 64; u += NTH) {    // L2 tile-3 frags
    const int ln = u & 63;
    const int ff = u >> 6;
    const int kt = ff % 5, m = ff / 5;
    const int n  = 48 + (ln & 15);
    const int kbb = (ln >> 4) * 8;
    f16x8 f;
    #pragma unroll
    for (int j = 0; j < 8; ++j) {
      const int k = kt*32 + kbb + j;
      float v = 0.f;
      if (k < 140) {
        if (m == 0)      v = args.in[19][n*140+k] * args.in[18][n*140+k];
        else if (m == 1) v = args.in[21][n*140+k] * args.in[18][n*140+k];
        else             v = args.in[23][n*140+k] + args.in[25][n*140+k];
      }
      f[j] = (_Float16)v;
    }
    *reinterpret_cast<f16x8*>(wt3 + (size_t)u * 8) = f;
  }
  for (int u = tid; u < 8 * 64; u += NTH) {     // FC frags
    const int ln = u & 63;
    const int ff = u >> 6;                       // ot*2+kt
    const int kt = ff & 1, ot = ff >> 1;
    f16x8 f;
    #pragma unroll
    for (int j = 0; j < 8; ++j)
      f[j] = (_Float16)args.in[27][(ot*16 + (ln & 15))*64 + kt*32 + (ln >> 4)*8 + j];
    *reinterpret_cast<f16x8*>(wfcs + (size_t)u * 8) = f;
  }
  if (tid < 128) {
    b0s[tid]       = (tid < 116) ? args.in[2][tid] : 0.f;
    b0s[128 + tid] = (tid < 116) ? args.in[4][tid] : 0.f;
    b0s[256 + tid] = (tid < 116) ? args.in[6][tid] + args.in[8][tid] : 0.f;
  }
  if (tid < 80) {
    b1s[tid]       = (tid < 76) ? args.in[11][tid] : 0.f;
    b1s[80 + tid]  = (tid < 76) ? args.in[13][tid] : 0.f;
    b1s[160 + tid] = (tid < 76) ? args.in[15][tid] + args.in[17][tid] : 0.f;
  }
  if (tid < 64) {
    b2s[tid]       = args.in[20][tid];
    b2s[64 + tid]  = args.in[22][tid];
    b2s[128 + tid] = args.in[24][tid] + args.in[26][tid];
    bfcs[tid]      = args.in[28][tid];
  }
  for (int i = tid; i < 2 * 16 * LD0; i += NTH) c0[0][i] = (_Float16)0.f;
  for (int i = tid; i < 2 * 16 * LD1; i += NTH) c1[0][i] = (_Float16)0.f;
  for (int i = tid; i < 2 * 16 * LD2; i += NTH) c2[0][i] = (_Float16)0.f;
  __syncthreads();
  // stage x(0): threads 0..511, float2 each
  const int rr = (tid & 511) >> 5, cc = (tid & 31) * 2;
  if (tid < 512) {
    const float2 v = *reinterpret_cast<const float2*>(
        xg + ((size_t)(wgBase + rr) * SEQT) * 64 + cc);
    f16x2 pk; pk[0] = (_Float16)v.x; pk[1] = (_Float16)v.y;
    *reinterpret_cast<f16x2*>(c0[0] + rr * LD0 + cc) = pk;
  }
  __syncthreads();

  const float* xp = xg + ((size_t)(wgBase + rr) * SEQT + 1) * 64 + cc;
  const int otb = (wv >= 13) ? (wv - 13) : 0;
  float* outp = args.out + ((size_t)(wgBase + r) * SEQT) * 64 + otb * 32 + 4 * g;

  // ---------- pipelined recurrence: one barrier per phase ----------
  // phase p: L0->h0(p), L1->h1(p-1), L2->h2(p-2), FC->y(p-3)
  #pragma unroll 1
  for (int p = 0; p < SEQT + 3; ++p) {
    const int cur = p & 1, nxt = cur ^ 1;

    float2 xv;
    const bool doX = (tid < 512) && (p < SEQT - 1);
    if (doX) xv = *reinterpret_cast<const float2*>(xp);

    if (wv < 8) {
      if (p < SEQT) {                       // L0 tile wv
        f32x4 a[3];
        const int nb = wv*16 + 4*g;
        init3(a, b0s, 128, nb);
        __builtin_amdgcn_s_setprio(1);
        mma_tile_ld<6>(a, wW, c0[cur], LD0, r, kb);
        __builtin_amdgcn_s_setprio(0);
        const f16x4 v = combine3(a);
        if (nb < 116) {
          *reinterpret_cast<f16x4*>(c1[nxt] + r*LD1 + nb)      = v;
          *reinterpret_cast<f16x4*>(c0[nxt] + r*LD0 + 64 + nb) = v;
        }
      }
    } else if (wv < 13) {
      if (p >= 1 && p <= SEQT) {            // L1 tile wv-8
        f32x4 a[3];
        const int nb = (wv-8)*16 + 4*g;
        init3(a, b1s, 80, nb);
        __builtin_amdgcn_s_setprio(1);
        mma_tile_ld<6>(a, wW, c1[cur], LD1, r, kb);
        __builtin_amdgcn_s_setprio(0);
        const f16x4 v = combine3(a);
        if (nb < 76) {
          *reinterpret_cast<f16x4*>(c1[nxt] + r*LD1 + 116 + nb) = v;
          *reinterpret_cast<f16x4*>(c2[nxt] + r*LD2 + nb)       = v;
        }
      }
    } else if (wv < 15) {
      if (p >= 3) {                         // FC o-tiles (wv-13)*2, +1 on h2(p-3)
        const int ot0 = (wv - 13) * 2;
        f32x4 fa0 = *reinterpret_cast<const f32x4*>(bfcs + ot0*16 + 4*g);
        f32x4 fa1 = *reinterpret_cast<const f32x4*>(bfcs + ot0*16 + 16 + 4*g);
        const f16x8 hb0 = loadB8u(c2[cur] + r*LD2 + 76 + kb);
        const f16x8 hb1 = loadB8u(c2[cur] + r*LD2 + 76 + 32 + kb);
        const f16x8 wf00 = *reinterpret_cast<const f16x8*>(wfcs + (size_t)((ot0*2    )*64 + lane)*8);
        const f16x8 wf01 = *reinterpret_cast<const f16x8*>(wfcs + (size_t)((ot0*2 + 1)*64 + lane)*8);
        const f16x8 wf10 = *reinterpret_cast<const f16x8*>(wfcs + (size_t)((ot0*2 + 2)*64 + lane)*8);
        const f16x8 wf11 = *reinterpret_cast<const f16x8*>(wfcs + (size_t)((ot0*2 + 3)*64 + lane)*8);
        fa0 = mfma16(wf00, hb0, fa0); fa0 = mfma16(wf01, hb1, fa0);
        fa1 = mfma16(wf10, hb0, fa1); fa1 = mfma16(wf11, hb1, fa1);
        *reinterpret_cast<f32x4*>(outp)      = fa0;
        *reinterpret_cast<f32x4*>(outp + 16) = fa1;
        outp += 64;
      }
      if (p >= 2 && p <= SEQT + 1) {        // L2 tile wv-13
        f32x4 a[3];
        const int nb = (wv-13)*16 + 4*g;
        init3(a, b2s, 64, nb);
        __builtin_amdgcn_s_setprio(1);
        mma_tile_ld<5>(a, wW, c2[cur], LD2, r, kb);
        __builtin_amdgcn_s_setprio(0);
        const f16x4 v = combine3(a);
        *reinterpret_cast<f16x4*>(c2[nxt] + r*LD2 + 76 + nb) = v;
      }
    } else {
      if (p >= 2 && p <= SEQT + 1) {        // L2 tiles 2 (regs) + 3 (LDS), shared B
        f32x4 a2[3], a3[3];
        init3(a2, b2s, 64, 32 + 4*g);
        init3(a3, b2s, 64, 48 + 4*g);
        __builtin_amdgcn_s_setprio(1);
        #pragma unroll
        for (int kt = 0; kt < 5; ++kt) {
          const f16x8 b = *reinterpret_cast<const f16x8*>(c2[cur] + r*LD2 + kt*32 + kb);
          #pragma unroll
          for (int m = 0; m < 3; ++m) {
            a2[m] = mfma16(wW[m*5 + kt], b, a2[m]);
            const f16x8 af = *reinterpret_cast<const f16x8*>(
                wt3 + (size_t)((m*5 + kt)*64 + lane) * 8);
            a3[m] = mfma16(af, b, a3[m]);
          }
        }
        __builtin_amdgcn_s_setprio(0);
        const f16x4 v2 = combine3(a2);
        const f16x4 v3 = combine3(a3);
        *reinterpret_cast<f16x4*>(c2[nxt] + r*LD2 + 76 + 32 + 4*g) = v2;
        *reinterpret_cast<f16x4*>(c2[nxt] + r*LD2 + 76 + 48 + 4*g) = v3;
      }
    }

    if (doX) {   // stage x(p+1) into c0[nxt][:,0:64)
      f16x2 pk; pk[0] = (_Float16)xv.x; pk[1] = (_Float16)xv.y;
      *reinterpret_cast<f16x2*>(c0[nxt] + rr * LD0 + cc) = pk;
      xp += 64;
    }
    __syncthreads();
  }
}

extern "C" void kernel_launch(void* const* d_in, const int* in_sizes, int n_in,
                              void* d_out, int out_size, void* d_ws, size_t ws_size,
                              hipStream_t stream) {
  KArgs args;
  for (int i = 0; i < 30; ++i) args.in[i] = (const float*)d_in[i];
  args.out = (float*)d_out;
  ncp_fused<<<dim3(32), dim3(NTH), 0, stream>>>(args);
}